// Round 6
// baseline (155.504 us; speedup 1.0000x reference)
//
#include <hip/hip_runtime.h>
#include <hip/hip_bf16.h>

// GCN layer: out = spmm(adj, x @ W) + bias
// Inputs: x[50000,128] f32, weight[128,128] f32, bias[128] f32,
//         edge_vals[625000] f32, edge_rows[625000] i32, edge_cols[625000] i32
// Output: out[50000,128] f32
//
// Round 6: kill the random 8-B scatter (41 MB partial-line write traffic for
// a 5 MB payload -> ~930 GB/s wall). New pipeline, 4 dispatches:
//   initw  : wt = bf16(w^T); slab allocators bucket_cur[b] = b*SLAB
//   bin    : LDS-staged binning of 8-B edge records into 98 coarse slabs
//            (512 rows each); global writes are ~334-B contiguous segments
//   gemm   : support = bf16(x @ W) via MFMA (unchanged)
//   bspmm  : block per 64-row window; filter + LDS counting-sort own rows
//            from the slab, then register-accumulated pull, coalesced out.

#define F_DIM 128

#define NBC 98                 // coarse buckets: row >> 9 (512 rows each)
#define SLAB 7360              // records per slab (mean 6378, +12 sigma)

#define BIN_T 256
#define BIN_EPT 16
#define BIN_CHUNK (BIN_T * BIN_EPT)     // 4096 edges per block

#define SPMM_T 512
#define SPMM_EPT 8
#define SPMM_CHUNK (SPMM_T * SPMM_EPT)  // 4096 records per chunk

typedef short bf16x8 __attribute__((ext_vector_type(8)));
typedef float f32x4 __attribute__((ext_vector_type(4)));

__device__ __forceinline__ unsigned short f2bf(float f) {
    unsigned int u = __float_as_uint(f);
    u += 0x7FFFu + ((u >> 16) & 1u);   // round-to-nearest-even
    return (unsigned short)(u >> 16);
}

// ---- initw: wt[n][k] = bf16(w[k][n]); bucket_cur[b] = b*SLAB -------------
__global__ void __launch_bounds__(256)
initw_kernel(const float* __restrict__ w, unsigned short* __restrict__ wt,
             int* __restrict__ bucket_cur) {
    if (blockIdx.x == 64) {
        int t = threadIdx.x;
        if (t < NBC) bucket_cur[t] = t * SLAB;
        return;
    }
    int idx = blockIdx.x * 256 + threadIdx.x;
    int n = idx >> 7, k = idx & 127;
    wt[n * F_DIM + k] = f2bf(w[k * F_DIM + n]);
}

// ---- bin: stage BIN_CHUNK edges, sort by coarse bucket in LDS, flush -----
__global__ void __launch_bounds__(BIN_T)
bin_kernel(const int* __restrict__ rows, const int* __restrict__ cols,
           const float* __restrict__ vals, int* __restrict__ bucket_cur,
           uint2* __restrict__ ebin, int n_edges) {
    __shared__ int lcnt[NBC];            // per-bucket count, then running pos
    __shared__ int lbase[NBC];           // exclusive prefix
    __shared__ int garr[NBC];            // reserved global base
    __shared__ int partial[128];         // scan workspace (NBC <= 128)
    __shared__ uint2 srec[BIN_CHUNK];    // bucket-sorted records (32 KB)
    __shared__ unsigned char sbkt[BIN_CHUNK];

    const int t = threadIdx.x;
    const int base = blockIdx.x * BIN_CHUNK;

    for (int i = t; i < NBC; i += BIN_T) lcnt[i] = 0;
    __syncthreads();

    unsigned int mykey[BIN_EPT];
    float myval[BIN_EPT];
    bool myok[BIN_EPT];
#pragma unroll
    for (int j = 0; j < BIN_EPT; j++) {
        int e = base + j * BIN_T + t;
        myok[j] = (e < n_edges);
        if (myok[j]) {
            int r = rows[e];
            int c = cols[e];
            myval[j] = vals[e];
            mykey[j] = ((unsigned)r << 16) | (unsigned)c;
            atomicAdd(&lcnt[r >> 9], 1);
        }
    }
    __syncthreads();

    // exclusive scan of lcnt[0..NBC) via Hillis-Steele over 128 slots
    if (t < 128) partial[t] = (t < NBC) ? lcnt[t] : 0;
    __syncthreads();
    for (int d = 1; d < 128; d <<= 1) {
        int u = (t < 128 && t >= d) ? partial[t - d] : 0;
        __syncthreads();
        if (t < 128) partial[t] += u;
        __syncthreads();
    }
    if (t < NBC) {
        lbase[t] = partial[t] - lcnt[t];
        if (lcnt[t] > 0) garr[t] = atomicAdd(&bucket_cur[t], lcnt[t]);
    }
    __syncthreads();
    // reuse lcnt as running placement position
    if (t < NBC) lcnt[t] = lbase[t];
    __syncthreads();

#pragma unroll
    for (int j = 0; j < BIN_EPT; j++) {
        if (myok[j]) {
            int b = (int)(mykey[j] >> 25);        // row>>9
            int p = atomicAdd(&lcnt[b], 1);
            srec[p] = make_uint2(mykey[j], __float_as_uint(myval[j]));
            sbkt[p] = (unsigned char)b;
        }
    }
    __syncthreads();

    const int m = min(BIN_CHUNK, n_edges - base);
    for (int i = t; i < m; i += BIN_T) {
        int b = sbkt[i];
        int dst = garr[b] + (i - lbase[b]);
        if (dst < (b + 1) * SLAB) ebin[dst] = srec[i];   // slab overflow guard
    }
}

// ---- GEMM: support_bf16 = bf16(x @ W) via MFMA ---------------------------
__global__ void __launch_bounds__(256)
gemm_mfma_kernel(const float* __restrict__ x, const unsigned short* __restrict__ wt,
                 unsigned short* __restrict__ support) {
    const int tid = threadIdx.x;
    const int wid = tid >> 6;
    const int lane = tid & 63;
    const int l15 = lane & 15;
    const int lhi = lane >> 4;           // 0..3

    const int m0 = (blockIdx.x >> 1) * 16;           // 3125*16 = 50000 exact
    const int n0 = (blockIdx.x & 1) * 64 + wid * 16;

    const float* xrow = x + (size_t)(m0 + l15) * F_DIM + lhi * 8;
    const unsigned short* wrow = wt + (size_t)(n0 + l15) * F_DIM + lhi * 8;

    f32x4 acc = {0.f, 0.f, 0.f, 0.f};
#pragma unroll
    for (int k0 = 0; k0 < F_DIM; k0 += 32) {
        float4 xa = *reinterpret_cast<const float4*>(xrow + k0);
        float4 xb = *reinterpret_cast<const float4*>(xrow + k0 + 4);
        bf16x8 a, b;
        a[0] = (short)f2bf(xa.x); a[1] = (short)f2bf(xa.y);
        a[2] = (short)f2bf(xa.z); a[3] = (short)f2bf(xa.w);
        a[4] = (short)f2bf(xb.x); a[5] = (short)f2bf(xb.y);
        a[6] = (short)f2bf(xb.z); a[7] = (short)f2bf(xb.w);
        b = *reinterpret_cast<const bf16x8*>(wrow + k0);
        acc = __builtin_amdgcn_mfma_f32_16x16x32_bf16(a, b, acc, 0, 0, 0);
    }

    unsigned short* sp = support + (size_t)(m0 + 4 * lhi) * F_DIM + n0 + l15;
#pragma unroll
    for (int i = 0; i < 4; i++)
        sp[(size_t)i * F_DIM] = f2bf(acc[i]);
}

// ---- bspmm: block per 64-row window; filter+sort slab records in LDS,
//      register-accumulate per row, coalesced out writes + bias ------------
__global__ void __launch_bounds__(SPMM_T)
bspmm_kernel(const unsigned short* __restrict__ support,
             const uint2* __restrict__ ebin, const int* __restrict__ bucket_cur,
             const float* __restrict__ bias, float* __restrict__ out,
             int n_nodes) {
    __shared__ uint2 sdst[SPMM_CHUNK];   // row-sorted records (32 KB)
    __shared__ int lbase[65];
    __shared__ int lpos[64];
    __shared__ int scan_tmp[64];

    const int blk = blockIdx.x;
    const int w0 = blk * 64;             // first row of this window
    const int cb = blk >> 3;             // coarse bucket (8 windows per slab)
    const int s = cb * SLAB;
    const int e = min(bucket_cur[cb], (cb + 1) * SLAB);

    const int t = threadIdx.x;
    const int wid = t >> 6;
    const int lane = t & 63;

    float accv[8][2];
#pragma unroll
    for (int j = 0; j < 8; j++) { accv[j][0] = 0.f; accv[j][1] = 0.f; }

    for (int cs = s; cs < e; cs += SPMM_CHUNK) {
        if (t < 64) lpos[t] = 0;
        __syncthreads();

        uint2 stash[SPMM_EPT];
        int srow[SPMM_EPT];
#pragma unroll
        for (int j = 0; j < SPMM_EPT; j++) {
            int i = cs + j * SPMM_T + t;
            srow[j] = -1;
            if (i < e) {
                uint2 rec = ebin[i];
                int rr = (int)(rec.x >> 16) - w0;
                if ((unsigned)rr < 64u) {
                    stash[j] = rec;
                    srow[j] = rr;
                    atomicAdd(&lpos[rr], 1);
                }
            }
        }
        __syncthreads();

        // exclusive scan of the 64 row counts
        if (t < 64) scan_tmp[t] = lpos[t];
        __syncthreads();
        for (int d = 1; d < 64; d <<= 1) {
            int u = (t < 64 && t >= d) ? scan_tmp[t - d] : 0;
            __syncthreads();
            if (t < 64) scan_tmp[t] += u;
            __syncthreads();
        }
        if (t < 64) {
            lbase[t + 1] = scan_tmp[t];
            lpos[t] = scan_tmp[t] - lpos[t];   // exclusive base, running
            if (t == 0) lbase[0] = 0;
        }
        __syncthreads();

#pragma unroll
        for (int j = 0; j < SPMM_EPT; j++) {
            if (srow[j] >= 0) {
                int p = atomicAdd(&lpos[srow[j]], 1);
                sdst[p] = stash[j];
            }
        }
        __syncthreads();

        // compute: wave wid owns rows wid*8 .. wid*8+7
#pragma unroll
        for (int rr = 0; rr < 8; rr++) {
            const int r = wid * 8 + rr;
            const int i0 = lbase[r];
            const int i1 = lbase[r + 1];
            for (int i = i0; i < i1; i++) {
                uint2 rec = sdst[i];                     // wave-uniform (broadcast)
                float v = __uint_as_float(rec.y);
                int col = (int)(rec.x & 0xffffu);
                unsigned sv = *reinterpret_cast<const unsigned*>(
                    support + (size_t)col * F_DIM + lane * 2);
                accv[rr][0] += v * __uint_as_float(sv << 16);
                accv[rr][1] += v * __uint_as_float(sv & 0xFFFF0000u);
            }
        }
        __syncthreads();   // protect lbase/sdst before next chunk
    }

    const float2 bb = *reinterpret_cast<const float2*>(bias + lane * 2);
#pragma unroll
    for (int rr = 0; rr < 8; rr++) {
        int row = w0 + wid * 8 + rr;
        if (row < n_nodes) {
            float2 o = make_float2(accv[rr][0] + bb.x, accv[rr][1] + bb.y);
            *reinterpret_cast<float2*>(out + (size_t)row * F_DIM + lane * 2) = o;
        }
    }
}

extern "C" void kernel_launch(void* const* d_in, const int* in_sizes, int n_in,
                              void* d_out, int out_size, void* d_ws, size_t ws_size,
                              hipStream_t stream) {
    const float* x      = (const float*)d_in[0];
    const float* weight = (const float*)d_in[1];
    const float* bias   = (const float*)d_in[2];
    const float* evals  = (const float*)d_in[3];
    const int*   erows  = (const int*)d_in[4];
    const int*   ecols  = (const int*)d_in[5];
    float* out = (float*)d_out;

    const int n_nodes = in_sizes[0] / F_DIM;   // 50000
    const int n_edges = in_sizes[3];           // 625000

    // Workspace layout (~18.6 MB)
    unsigned short* support = (unsigned short*)d_ws;                  // n_nodes*128 bf16
    unsigned short* wt      = support + (size_t)n_nodes * F_DIM;      // 128*128 bf16
    int* bucket_cur = (int*)(wt + F_DIM * F_DIM);                     // NBC
    uintptr_t ep = (uintptr_t)(bucket_cur + NBC);
    ep = (ep + 15) & ~(uintptr_t)15;
    uint2* ebin = (uint2*)ep;                                         // NBC*SLAB*8 B

    // 1) wt = bf16(w^T); slab allocators
    initw_kernel<<<65, 256, 0, stream>>>(weight, wt, bucket_cur);

    // 2) bin edges into coarse slabs (coalesced segment writes)
    int bin_blocks = (n_edges + BIN_CHUNK - 1) / BIN_CHUNK;           // 153
    bin_kernel<<<bin_blocks, BIN_T, 0, stream>>>(erows, ecols, evals,
                                                 bucket_cur, ebin, n_edges);

    // 3) support = bf16(x @ W) via MFMA
    gemm_mfma_kernel<<<(n_nodes / 16) * 2, 256, 0, stream>>>(x, wt, support);

    // 4) windowed pull-spmm (no atomics, coalesced writes)
    int nwin = (n_nodes + 63) / 64;                                   // 782
    bspmm_kernel<<<nwin, SPMM_T, 0, stream>>>(support, ebin, bucket_cur,
                                              bias, out, n_nodes);
}